// Round 1
// baseline (414.404 us; speedup 1.0000x reference)
//
#include <hip/hip_runtime.h>
#include <stdint.h>

#define N_ROWS 8192
#define C_IN   4096
#define C_OUT  4096
#define KWORDS (C_IN/32)   // 128 u32 per row
#define KW64   (C_IN/64)   // 64 u64 per row

#define BM 128
#define BN 128
#define KW 32              // u32 words per K chunk (1024 bits)
#define LDS_STRIDE 36      // padded (36 words = 144 B, 16B-aligned rows)

// ---------------- pack signs + partial sum of |v| ----------------
__global__ void pack_reduce_kernel(const float* __restrict__ src, int n64,
                                   unsigned long long* __restrict__ bits,
                                   float* __restrict__ partials) {
    const int lane = threadIdx.x & 63;
    const int warp = threadIdx.x >> 6;
    const int waves_per_block = blockDim.x >> 6;
    const int gwave  = blockIdx.x * waves_per_block + warp;
    const int nwaves = gridDim.x * waves_per_block;

    float acc = 0.f;
    for (int g = gwave; g < n64; g += nwaves) {
        float v = src[(long long)g * 64 + lane];
        acc += fabsf(v);
        unsigned long long m = __ballot(v > 0.0f);
        if (lane == 0) bits[g] = m;
    }
    // wave reduce (deterministic)
    for (int off = 32; off > 0; off >>= 1) acc += __shfl_down(acc, off, 64);
    __shared__ float sacc[8];
    if (lane == 0) sacc[warp] = acc;
    __syncthreads();
    if (threadIdx.x == 0) {
        float s = 0.f;
        for (int i = 0; i < waves_per_block; ++i) s += sacc[i];
        partials[blockIdx.x] = s;
    }
}

// ---------------- deterministic final reduction -> alpha*betta ----------------
__global__ void finalize_kernel(const float* __restrict__ part_x, int nx,
                                const float* __restrict__ part_w, int nw,
                                float* __restrict__ out_ab) {
    __shared__ float s[256];
    float ax = 0.f;
    for (int i = threadIdx.x; i < nx; i += 256) ax += part_x[i];
    s[threadIdx.x] = ax; __syncthreads();
    for (int st = 128; st > 0; st >>= 1) {
        if (threadIdx.x < st) s[threadIdx.x] += s[threadIdx.x + st];
        __syncthreads();
    }
    float sumx = s[0];
    __syncthreads();
    float aw = 0.f;
    for (int i = threadIdx.x; i < nw; i += 256) aw += part_w[i];
    s[threadIdx.x] = aw; __syncthreads();
    for (int st = 128; st > 0; st >>= 1) {
        if (threadIdx.x < st) s[threadIdx.x] += s[threadIdx.x + st];
        __syncthreads();
    }
    if (threadIdx.x == 0) {
        float sumw = s[0];
        float alpha = sumw / (float)((long long)C_OUT * C_IN);
        float betta = sumx / (float)((long long)N_ROWS * C_IN);
        out_ab[0] = alpha * betta;
    }
}

// ---------------- XOR-popcount GEMM ----------------
__launch_bounds__(256, 2)
__global__ void xnor_gemm_kernel(const uint32_t* __restrict__ xbits,
                                 const uint32_t* __restrict__ wbits,
                                 const float* __restrict__ bias,
                                 const float* __restrict__ ab_ptr,
                                 float* __restrict__ out) {
    __shared__ uint32_t a_lds[BM * LDS_STRIDE];
    __shared__ uint32_t b_lds[BN * LDS_STRIDE];

    const int t  = threadIdx.x;
    const int tr = t >> 4;   // 0..15
    const int tc = t & 15;   // 0..15
    const int brow = blockIdx.y * BM;
    const int bcol = blockIdx.x * BN;

    uint32_t acc[8][8];
#pragma unroll
    for (int i = 0; i < 8; ++i)
#pragma unroll
        for (int j = 0; j < 8; ++j) acc[i][j] = 0u;

    const uint32_t* aptr = xbits + (long long)brow * KWORDS;
    const uint32_t* bptr = wbits + (long long)bcol * KWORDS;

    for (int chunk = 0; chunk < KWORDS / KW; ++chunk) {
        // stage: 128 rows x 8 uint4 groups per matrix; 256 threads x 4 groups
#pragma unroll
        for (int sIdx = 0; sIdx < 4; ++sIdx) {
            int g   = t + sIdx * 256;
            int row = g >> 3;
            int wg  = g & 7;
            uint4 va = *reinterpret_cast<const uint4*>(aptr + (long long)row * KWORDS + chunk * KW + wg * 4);
            uint4 vb = *reinterpret_cast<const uint4*>(bptr + (long long)row * KWORDS + chunk * KW + wg * 4);
            *reinterpret_cast<uint4*>(&a_lds[row * LDS_STRIDE + wg * 4]) = va;
            *reinterpret_cast<uint4*>(&b_lds[row * LDS_STRIDE + wg * 4]) = vb;
        }
        __syncthreads();

#pragma unroll 2
        for (int kw = 0; kw < KW / 4; ++kw) {
            uint4 a[8], b[8];
#pragma unroll
            for (int i = 0; i < 8; ++i)
                a[i] = *reinterpret_cast<const uint4*>(&a_lds[(tr + i * 16) * LDS_STRIDE + kw * 4]);
#pragma unroll
            for (int j = 0; j < 8; ++j)
                b[j] = *reinterpret_cast<const uint4*>(&b_lds[(tc + j * 16) * LDS_STRIDE + kw * 4]);
#pragma unroll
            for (int i = 0; i < 8; ++i)
#pragma unroll
                for (int j = 0; j < 8; ++j) {
                    acc[i][j] += __popc(a[i].x ^ b[j].x);
                    acc[i][j] += __popc(a[i].y ^ b[j].y);
                    acc[i][j] += __popc(a[i].z ^ b[j].z);
                    acc[i][j] += __popc(a[i].w ^ b[j].w);
                }
        }
        __syncthreads();
    }

    const float ab = ab_ptr[0];
#pragma unroll
    for (int i = 0; i < 8; ++i) {
        int row = brow + tr + i * 16;
        float* orow = out + (long long)row * C_OUT;
#pragma unroll
        for (int j = 0; j < 8; ++j) {
            int col = bcol + tc + j * 16;
            float dot = (float)(C_IN - 2 * (int)acc[i][j]);
            orow[col] = dot * ab + bias[col];
        }
    }
}

extern "C" void kernel_launch(void* const* d_in, const int* in_sizes, int n_in,
                              void* d_out, int out_size, void* d_ws, size_t ws_size,
                              hipStream_t stream) {
    const float* x    = (const float*)d_in[0];
    const float* w    = (const float*)d_in[1];
    const float* bias = (const float*)d_in[2];
    float* out = (float*)d_out;

    char* ws = (char*)d_ws;
    float* red    = (float*)ws;        // red[0] = alpha*betta
    float* part_x = red + 16;          // 2048 partials
    float* part_w = part_x + 2048;     // 1024 partials
    unsigned long long* xbits = (unsigned long long*)(ws + 16384);
    unsigned long long* wbits = xbits + (size_t)N_ROWS * KW64;

    pack_reduce_kernel<<<2048, 256, 0, stream>>>(x, N_ROWS * C_IN / 64, xbits, part_x);
    pack_reduce_kernel<<<1024, 256, 0, stream>>>(w, C_OUT * C_IN / 64, wbits, part_w);
    finalize_kernel<<<1, 256, 0, stream>>>(part_x, 2048, part_w, 1024, red);

    dim3 grid(C_OUT / BN, N_ROWS / BM);
    xnor_gemm_kernel<<<grid, 256, 0, stream>>>((const uint32_t*)xbits,
                                               (const uint32_t*)wbits,
                                               bias, red, out);
}

// Round 2
// 196.965 us; speedup vs baseline: 2.1039x; 2.1039x over previous
//
#include <hip/hip_runtime.h>
#include <stdint.h>

#define N_ROWS 8192
#define C_IN   4096
#define C_OUT  4096

typedef int v4i  __attribute__((ext_vector_type(4)));
typedef int v16i __attribute__((ext_vector_type(16)));

// ======================================================================
// Path A: i8-MFMA XNOR GEMM
// ======================================================================

// ---- pack f32 -> i8 sign (+1 / -1) + partial sum of |v| ----
__global__ void pack_i8_kernel(const float* __restrict__ src, long long n8,
                               uint32_t* __restrict__ sgn,   // 2 u32 per 8 floats
                               float* __restrict__ partials) {
    long long idx0 = (long long)blockIdx.x * blockDim.x + threadIdx.x;
    long long stride = (long long)gridDim.x * blockDim.x;
    float acc = 0.f;
    for (long long g = idx0; g < n8; g += stride) {
        const float4* p = (const float4*)(src + g * 8);
        float4 v0 = p[0], v1 = p[1];
        uint32_t b0 = (v0.x > 0.f ? 0x01u : 0xFFu)
                    | (v0.y > 0.f ? 0x01u : 0xFFu) << 8
                    | (v0.z > 0.f ? 0x01u : 0xFFu) << 16
                    | (v0.w > 0.f ? 0x01u : 0xFFu) << 24;
        uint32_t b1 = (v1.x > 0.f ? 0x01u : 0xFFu)
                    | (v1.y > 0.f ? 0x01u : 0xFFu) << 8
                    | (v1.z > 0.f ? 0x01u : 0xFFu) << 16
                    | (v1.w > 0.f ? 0x01u : 0xFFu) << 24;
        uint2 st; st.x = b0; st.y = b1;
        *reinterpret_cast<uint2*>(sgn + g * 2) = st;
        acc += fabsf(v0.x) + fabsf(v0.y) + fabsf(v0.z) + fabsf(v0.w)
             + fabsf(v1.x) + fabsf(v1.y) + fabsf(v1.z) + fabsf(v1.w);
    }
    // wave reduce (deterministic)
    for (int off = 32; off > 0; off >>= 1) acc += __shfl_down(acc, off, 64);
    __shared__ float sacc[8];
    int lane = threadIdx.x & 63, warp = threadIdx.x >> 6;
    if (lane == 0) sacc[warp] = acc;
    __syncthreads();
    if (threadIdx.x == 0) {
        float s = 0.f;
        int nw = blockDim.x >> 6;
        for (int i = 0; i < nw; ++i) s += sacc[i];
        partials[blockIdx.x] = s;
    }
}

// ---- deterministic final reduction -> alpha*betta ----
__global__ void finalize_kernel(const float* __restrict__ part_x, int nx,
                                const float* __restrict__ part_w, int nw,
                                float* __restrict__ out_ab) {
    __shared__ float s[256];
    float ax = 0.f;
    for (int i = threadIdx.x; i < nx; i += 256) ax += part_x[i];
    s[threadIdx.x] = ax; __syncthreads();
    for (int st = 128; st > 0; st >>= 1) {
        if (threadIdx.x < st) s[threadIdx.x] += s[threadIdx.x + st];
        __syncthreads();
    }
    float sumx = s[0];
    __syncthreads();
    float aw = 0.f;
    for (int i = threadIdx.x; i < nw; i += 256) aw += part_w[i];
    s[threadIdx.x] = aw; __syncthreads();
    for (int st = 128; st > 0; st >>= 1) {
        if (threadIdx.x < st) s[threadIdx.x] += s[threadIdx.x + st];
        __syncthreads();
    }
    if (threadIdx.x == 0) {
        float sumw = s[0];
        float alpha = sumw / (float)((long long)C_OUT * C_IN);
        float betta = sumx / (float)((long long)N_ROWS * C_IN);
        out_ab[0] = alpha * betta;
    }
}

// ---- i8 MFMA GEMM: 256x256 tile, 8 waves, BK=64, dbuf 2-phase ----
#define BM 256
#define BN 256
#define BK 64
#define NCHUNK (C_IN / BK)

__launch_bounds__(512, 1)
__global__ void xnor_gemm_i8(const int8_t* __restrict__ xs,
                             const int8_t* __restrict__ wsg,
                             const float* __restrict__ bias,
                             const float* __restrict__ ab_ptr,
                             float* __restrict__ out) {
    __shared__ __align__(16) int8_t lds[2][2][BM * BK];  // 64 KB

    const int t    = threadIdx.x;
    const int lane = t & 63;
    const int hi   = lane >> 5;
    const int r    = lane & 31;
    const int wid  = t >> 6;     // 0..7
    const int wr   = wid >> 2;   // 0..1
    const int wc   = wid & 3;    // 0..3

    // XCD-aware swizzle over 512 blocks (divisible by 8)
    int id  = blockIdx.x;
    int swz = (id & 7) * 64 + (id >> 3);
    const int brow = (swz >> 4) * BM;   // 32 m-tiles
    const int bcol = (swz & 15) * BN;   // 16 n-tiles

    // per-thread staging slots (2 per matrix); slot -> (row, phys word)
    // logical word = phys ^ ((row>>1)&3)  [pre-swizzled source, linear dest]
    int s_row[2], s_off[2];
#pragma unroll
    for (int i = 0; i < 2; ++i) {
        int slot = i * 512 + t;
        int row  = slot >> 2;
        int wl   = (slot & 3) ^ ((row >> 1) & 3);
        s_row[i] = row;
        s_off[i] = wl * 16;
    }

    auto stage = [&](int buf, int chunk) {
#pragma unroll
        for (int i = 0; i < 2; ++i) {
            int slot = i * 512 + t;
            const int8_t* ga = xs + (size_t)(brow + s_row[i]) * C_IN + chunk * BK + s_off[i];
            __builtin_amdgcn_global_load_lds(
                (const __attribute__((address_space(1))) void*)ga,
                (__attribute__((address_space(3))) void*)(&lds[buf][0][slot * 16]), 16, 0, 0);
            const int8_t* gb = wsg + (size_t)(bcol + s_row[i]) * C_IN + chunk * BK + s_off[i];
            __builtin_amdgcn_global_load_lds(
                (const __attribute__((address_space(1))) void*)gb,
                (__attribute__((address_space(3))) void*)(&lds[buf][1][slot * 16]), 16, 0, 0);
        }
    };

    v16i acc[4][2] = {};

    stage(0, 0);
    __syncthreads();

    for (int chunk = 0; chunk < NCHUNK; ++chunk) {
        int cur = chunk & 1;
        if (chunk + 1 < NCHUNK) stage(cur ^ 1, chunk + 1);
#pragma unroll
        for (int kk = 0; kk < 2; ++kk) {
            v4i a[4], b[2];
#pragma unroll
            for (int m = 0; m < 4; ++m) {
                int row = wr * 128 + m * 32 + r;
                int s   = (kk * 2 + hi) ^ ((row >> 1) & 3);
                a[m] = *(const v4i*)(&lds[cur][0][row * BK + s * 16]);
            }
#pragma unroll
            for (int n = 0; n < 2; ++n) {
                int row = wc * 64 + n * 32 + r;
                int s   = (kk * 2 + hi) ^ ((row >> 1) & 3);
                b[n] = *(const v4i*)(&lds[cur][1][row * BK + s * 16]);
            }
#pragma unroll
            for (int m = 0; m < 4; ++m)
#pragma unroll
                for (int n = 0; n < 2; ++n)
                    acc[m][n] = __builtin_amdgcn_mfma_i32_32x32x32_i8(a[m], b[n], acc[m][n], 0, 0, 0);
        }
        __syncthreads();
    }

    const float ab = ab_ptr[0];
#pragma unroll
    for (int m = 0; m < 4; ++m) {
#pragma unroll
        for (int n = 0; n < 2; ++n) {
            int col = bcol + wc * 64 + n * 32 + r;
            float bv = bias[col];
#pragma unroll
            for (int reg = 0; reg < 16; ++reg) {
                int rowf = (reg & 3) + 8 * (reg >> 2) + 4 * hi;
                int grow = brow + wr * 128 + m * 32 + rowf;
                out[(size_t)grow * C_OUT + col] = (float)acc[m][n][reg] * ab + bv;
            }
        }
    }
}

// ======================================================================
// Path B (fallback if ws too small): bit-pack + popcount GEMM (round-0)
// ======================================================================
#define KWORDS (C_IN/32)
#define KW64   (C_IN/64)
#define PBM 128
#define PBN 128
#define PKW 32
#define LDS_STRIDE 36

__global__ void pack_bits_kernel(const float* __restrict__ src, int n64,
                                 unsigned long long* __restrict__ bits,
                                 float* __restrict__ partials) {
    const int lane = threadIdx.x & 63;
    const int warp = threadIdx.x >> 6;
    const int waves_per_block = blockDim.x >> 6;
    const int gwave  = blockIdx.x * waves_per_block + warp;
    const int nwaves = gridDim.x * waves_per_block;
    float acc = 0.f;
    for (int g = gwave; g < n64; g += nwaves) {
        float v = src[(long long)g * 64 + lane];
        acc += fabsf(v);
        unsigned long long m = __ballot(v > 0.0f);
        if (lane == 0) bits[g] = m;
    }
    for (int off = 32; off > 0; off >>= 1) acc += __shfl_down(acc, off, 64);
    __shared__ float sacc[8];
    if (lane == 0) sacc[warp] = acc;
    __syncthreads();
    if (threadIdx.x == 0) {
        float s = 0.f;
        for (int i = 0; i < waves_per_block; ++i) s += sacc[i];
        partials[blockIdx.x] = s;
    }
}

__launch_bounds__(256, 2)
__global__ void xnor_gemm_pop(const uint32_t* __restrict__ xbits,
                              const uint32_t* __restrict__ wbits,
                              const float* __restrict__ bias,
                              const float* __restrict__ ab_ptr,
                              float* __restrict__ out) {
    __shared__ uint32_t a_lds[PBM * LDS_STRIDE];
    __shared__ uint32_t b_lds[PBN * LDS_STRIDE];
    const int t  = threadIdx.x;
    const int tr = t >> 4;
    const int tc = t & 15;
    const int brow = blockIdx.y * PBM;
    const int bcol = blockIdx.x * PBN;
    uint32_t acc[8][8];
#pragma unroll
    for (int i = 0; i < 8; ++i)
#pragma unroll
        for (int j = 0; j < 8; ++j) acc[i][j] = 0u;
    const uint32_t* aptr = xbits + (long long)brow * KWORDS;
    const uint32_t* bptr = wbits + (long long)bcol * KWORDS;
    for (int chunk = 0; chunk < KWORDS / PKW; ++chunk) {
#pragma unroll
        for (int sIdx = 0; sIdx < 4; ++sIdx) {
            int g   = t + sIdx * 256;
            int row = g >> 3;
            int wg  = g & 7;
            uint4 va = *reinterpret_cast<const uint4*>(aptr + (long long)row * KWORDS + chunk * PKW + wg * 4);
            uint4 vb = *reinterpret_cast<const uint4*>(bptr + (long long)row * KWORDS + chunk * PKW + wg * 4);
            *reinterpret_cast<uint4*>(&a_lds[row * LDS_STRIDE + wg * 4]) = va;
            *reinterpret_cast<uint4*>(&b_lds[row * LDS_STRIDE + wg * 4]) = vb;
        }
        __syncthreads();
#pragma unroll 2
        for (int kw = 0; kw < PKW / 4; ++kw) {
            uint4 a[8], b[8];
#pragma unroll
            for (int i = 0; i < 8; ++i)
                a[i] = *reinterpret_cast<const uint4*>(&a_lds[(tr + i * 16) * LDS_STRIDE + kw * 4]);
#pragma unroll
            for (int j = 0; j < 8; ++j)
                b[j] = *reinterpret_cast<const uint4*>(&b_lds[(tc + j * 16) * LDS_STRIDE + kw * 4]);
#pragma unroll
            for (int i = 0; i < 8; ++i)
#pragma unroll
                for (int j = 0; j < 8; ++j) {
                    acc[i][j] += __popc(a[i].x ^ b[j].x);
                    acc[i][j] += __popc(a[i].y ^ b[j].y);
                    acc[i][j] += __popc(a[i].z ^ b[j].z);
                    acc[i][j] += __popc(a[i].w ^ b[j].w);
                }
        }
        __syncthreads();
    }
    const float ab = ab_ptr[0];
#pragma unroll
    for (int i = 0; i < 8; ++i) {
        int row = brow + tr + i * 16;
        float* orow = out + (long long)row * C_OUT;
#pragma unroll
        for (int j = 0; j < 8; ++j) {
            int col = bcol + tc + j * 16;
            float dot = (float)(C_IN - 2 * (int)acc[i][j]);
            orow[col] = dot * ab + bias[col];
        }
    }
}

// ======================================================================
extern "C" void kernel_launch(void* const* d_in, const int* in_sizes, int n_in,
                              void* d_out, int out_size, void* d_ws, size_t ws_size,
                              hipStream_t stream) {
    const float* x    = (const float*)d_in[0];
    const float* w    = (const float*)d_in[1];
    const float* bias = (const float*)d_in[2];
    float* out = (float*)d_out;

    char* ws = (char*)d_ws;
    float* red    = (float*)ws;        // red[0] = alpha*betta
    float* part_x = red + 16;          // 2048 partials
    float* part_w = part_x + 2048;     // 1024 partials

    const size_t need_i8 = 16384 + (size_t)(N_ROWS + C_OUT) * C_IN;  // ~50.3 MB

    if (ws_size >= need_i8) {
        int8_t* xs  = (int8_t*)(ws + 16384);
        int8_t* wsg = xs + (size_t)N_ROWS * C_IN;

        pack_i8_kernel<<<2048, 256, 0, stream>>>(x, (long long)N_ROWS * C_IN / 8,
                                                 (uint32_t*)xs, part_x);
        pack_i8_kernel<<<1024, 256, 0, stream>>>(w, (long long)C_OUT * C_IN / 8,
                                                 (uint32_t*)wsg, part_w);
        finalize_kernel<<<1, 256, 0, stream>>>(part_x, 2048, part_w, 1024, red);

        dim3 grid((N_ROWS / BM) * (C_OUT / BN));  // 512
        xnor_gemm_i8<<<grid, 512, 0, stream>>>(xs, wsg, bias, red, out);
    } else {
        unsigned long long* xbits = (unsigned long long*)(ws + 16384);
        unsigned long long* wbits = xbits + (size_t)N_ROWS * KW64;

        pack_bits_kernel<<<2048, 256, 0, stream>>>(x, N_ROWS * C_IN / 64, xbits, part_x);
        pack_bits_kernel<<<1024, 256, 0, stream>>>(w, C_OUT * C_IN / 64, wbits, part_w);
        finalize_kernel<<<1, 256, 0, stream>>>(part_x, 2048, part_w, 1024, red);

        dim3 grid(C_OUT / PBN, N_ROWS / PBM);
        xnor_gemm_pop<<<grid, 256, 0, stream>>>((const uint32_t*)xbits,
                                                (const uint32_t*)wbits,
                                                bias, red, out);
    }
}

// Round 3
// 189.227 us; speedup vs baseline: 2.1900x; 1.0409x over previous
//
#include <hip/hip_runtime.h>
#include <stdint.h>

#define N_ROWS 8192
#define C_IN   4096
#define C_OUT  4096

typedef int v4i  __attribute__((ext_vector_type(4)));
typedef int v16i __attribute__((ext_vector_type(16)));

// ======================================================================
// pack f32 -> i8 sign (+1/-1) in MFMA fragment order + partial sum |v|
//
// Fragment file layout (per matrix): frag[mt][kb][1024B], where
//   mt = row>>5 (32-row tile), kb = k>>5 (32-k block),
//   byte[(hi*32 + r)*16 + j] = sign(src[mt*32 + r][kb*32 + hi*16 + j])
// This is exactly the v_mfma_i32_32x32x32_i8 A/B operand layout
// (lane = hi*32+r holds 16 i8 at k = hi*16..hi*16+15), verified on HW
// by round-1 passing with this lane mapping.
// Thread g handles one 16-float group; dst address = g*16 (linear).
// ======================================================================
__global__ void pack_frag_kernel(const float* __restrict__ src, long long n16,
                                 uint4* __restrict__ frags,
                                 float* __restrict__ partials) {
    long long g0     = (long long)blockIdx.x * blockDim.x + threadIdx.x;
    long long stride = (long long)gridDim.x * blockDim.x;
    float acc = 0.f;
    for (long long g = g0; g < n16; g += stride) {
        long long f  = g >> 6;
        int lane16   = (int)(g & 63);
        long long mt = f >> 7;
        int kb       = (int)(f & 127);
        int r  = lane16 & 31;
        int hi = lane16 >> 5;
        const float4* p = (const float4*)(src + (mt * 32 + r) * (long long)C_IN
                                              + kb * 32 + hi * 16);
        uint32_t b[4];
#pragma unroll
        for (int q = 0; q < 4; ++q) {
            float4 v = p[q];
            b[q] = (v.x > 0.f ? 0x01u : 0xFFu)
                 | (v.y > 0.f ? 0x01u : 0xFFu) << 8
                 | (v.z > 0.f ? 0x01u : 0xFFu) << 16
                 | (v.w > 0.f ? 0x01u : 0xFFu) << 24;
            acc += fabsf(v.x) + fabsf(v.y) + fabsf(v.z) + fabsf(v.w);
        }
        uint4 st; st.x = b[0]; st.y = b[1]; st.z = b[2]; st.w = b[3];
        frags[g] = st;
    }
    // deterministic wave + block reduce
    for (int off = 32; off > 0; off >>= 1) acc += __shfl_down(acc, off, 64);
    __shared__ float sacc[8];
    int lane = threadIdx.x & 63, warp = threadIdx.x >> 6;
    if (lane == 0) sacc[warp] = acc;
    __syncthreads();
    if (threadIdx.x == 0) {
        float s = 0.f;
        int nw = blockDim.x >> 6;
        for (int i = 0; i < nw; ++i) s += sacc[i];
        partials[blockIdx.x] = s;
    }
}

// ---- deterministic final reduction -> alpha*betta ----
__global__ void finalize_kernel(const float* __restrict__ part_x, int nx,
                                const float* __restrict__ part_w, int nw,
                                float* __restrict__ out_ab) {
    __shared__ float s[256];
    float ax = 0.f;
    for (int i = threadIdx.x; i < nx; i += 256) ax += part_x[i];
    s[threadIdx.x] = ax; __syncthreads();
    for (int st = 128; st > 0; st >>= 1) {
        if (threadIdx.x < st) s[threadIdx.x] += s[threadIdx.x + st];
        __syncthreads();
    }
    float sumx = s[0];
    __syncthreads();
    float aw = 0.f;
    for (int i = threadIdx.x; i < nw; i += 256) aw += part_w[i];
    s[threadIdx.x] = aw; __syncthreads();
    for (int st = 128; st > 0; st >>= 1) {
        if (threadIdx.x < st) s[threadIdx.x] += s[threadIdx.x + st];
        __syncthreads();
    }
    if (threadIdx.x == 0) {
        float sumw = s[0];
        float alpha = sumw / (float)((long long)C_OUT * C_IN);
        float betta = sumx / (float)((long long)N_ROWS * C_IN);
        out_ab[0] = alpha * betta;
    }
}

// ======================================================================
// i8 MFMA GEMM on fragment-ordered operands.
// 256x256 block tile, 8 waves (2x4), each wave 128x64. BK=64 (2 kb).
// LDS staging is linear (slot*16); all ds_read_b128 at base+lane*16:
// conflict-free by construction, zero address math.
// ======================================================================
#define BM 256
#define BN 256
#define NCHUNK (C_IN / 64)         // 64
#define MT_STRIDE (128 * 1024)     // bytes per mt slab in frag file (128 kbs)

__launch_bounds__(512)
__global__ void xnor_gemm_i8(const uint8_t* __restrict__ Afrag,
                             const uint8_t* __restrict__ Bfrag,
                             const float* __restrict__ bias,
                             const float* __restrict__ ab_ptr,
                             float* __restrict__ out) {
    __shared__ __align__(16) uint8_t lds[2][2][16384];  // 64 KB

    const int t    = threadIdx.x;
    const int lane = t & 63;
    const int hi   = lane >> 5;
    const int r    = lane & 31;
    const int wid  = t >> 6;     // 0..7
    const int wr   = wid >> 2;   // 0..1
    const int wc   = wid & 3;    // 0..3

    // XCD-aware swizzle over 512 blocks (divisible by 8)
    int id  = blockIdx.x;
    int swz = (id & 7) * 64 + (id >> 3);
    const int brow = (swz >> 4) * BM;
    const int bcol = (swz & 15) * BN;

    const uint8_t* Abase = Afrag + (size_t)(brow >> 5) * MT_STRIDE;
    const uint8_t* Bbase = Bfrag + (size_t)(bcol >> 5) * MT_STRIDE;

    // staging slots: 1024 16B-frag-lanes per matrix, 2 per thread
    // slot s: mt_local = s>>7, kk = (s>>6)&1, ln = s&63
    auto stage = [&](int buf, int chunk) {
#pragma unroll
        for (int i = 0; i < 2; ++i) {
            int s   = i * 512 + t;
            int mtl = s >> 7;
            int kk  = (s >> 6) & 1;
            int ln  = s & 63;
            size_t goff = (size_t)mtl * MT_STRIDE + (size_t)(chunk * 2 + kk) * 1024 + ln * 16;
            __builtin_amdgcn_global_load_lds(
                (const __attribute__((address_space(1))) void*)(Abase + goff),
                (__attribute__((address_space(3))) void*)(&lds[buf][0][s * 16]), 16, 0, 0);
            __builtin_amdgcn_global_load_lds(
                (const __attribute__((address_space(1))) void*)(Bbase + goff),
                (__attribute__((address_space(3))) void*)(&lds[buf][1][s * 16]), 16, 0, 0);
        }
    };

    v16i acc[4][2] = {};

    stage(0, 0);
    __syncthreads();

    for (int chunk = 0; chunk < NCHUNK; ++chunk) {
        int cur = chunk & 1;
        if (chunk + 1 < NCHUNK) stage(cur ^ 1, chunk + 1);
#pragma unroll
        for (int kk = 0; kk < 2; ++kk) {
            v4i a[4], b[2];
#pragma unroll
            for (int m = 0; m < 4; ++m)
                a[m] = *(const v4i*)(&lds[cur][0][(((wr * 4 + m) * 2 + kk) * 64 + lane) * 16]);
#pragma unroll
            for (int n = 0; n < 2; ++n)
                b[n] = *(const v4i*)(&lds[cur][1][(((wc * 2 + n) * 2 + kk) * 64 + lane) * 16]);
#pragma unroll
            for (int m = 0; m < 4; ++m)
#pragma unroll
                for (int n = 0; n < 2; ++n)
                    acc[m][n] = __builtin_amdgcn_mfma_i32_32x32x32_i8(a[m], b[n], acc[m][n], 0, 0, 0);
        }
        __syncthreads();
    }

    const float ab = ab_ptr[0];
#pragma unroll
    for (int m = 0; m < 4; ++m) {
#pragma unroll
        for (int n = 0; n < 2; ++n) {
            int col = bcol + wc * 64 + n * 32 + r;
            float bv = bias[col];
#pragma unroll
            for (int reg = 0; reg < 16; ++reg) {
                int rowf = (reg & 3) + 8 * (reg >> 2) + 4 * hi;   // C/D layout (m74/m101)
                int grow = brow + wr * 128 + m * 32 + rowf;
                out[(size_t)grow * C_OUT + col] = (float)acc[m][n][reg] * ab + bv;
            }
        }
    }
}

// ======================================================================
extern "C" void kernel_launch(void* const* d_in, const int* in_sizes, int n_in,
                              void* d_out, int out_size, void* d_ws, size_t ws_size,
                              hipStream_t stream) {
    const float* x    = (const float*)d_in[0];
    const float* w    = (const float*)d_in[1];
    const float* bias = (const float*)d_in[2];
    float* out = (float*)d_out;

    char* ws = (char*)d_ws;
    float* red    = (float*)ws;        // red[0] = alpha*betta
    float* part_x = red + 16;          // 2048 partials
    float* part_w = part_x + 2048;     // 1024 partials
    uint8_t* xs  = (uint8_t*)(ws + 16384);                 // 33.55 MB frag file
    uint8_t* wsg = xs + (size_t)N_ROWS * C_IN;             // 16.78 MB frag file

    pack_frag_kernel<<<2048, 256, 0, stream>>>(x, (long long)N_ROWS * C_IN / 16,
                                               (uint4*)xs, part_x);
    pack_frag_kernel<<<1024, 256, 0, stream>>>(w, (long long)C_OUT * C_IN / 16,
                                               (uint4*)wsg, part_w);
    finalize_kernel<<<1, 256, 0, stream>>>(part_x, 2048, part_w, 1024, red);

    dim3 grid((N_ROWS / BM) * (C_OUT / BN));  // 512
    xnor_gemm_i8<<<grid, 512, 0, stream>>>(xs, wsg, bias, red, out);
}

// Round 5
// 188.488 us; speedup vs baseline: 2.1986x; 1.0039x over previous
//
#include <hip/hip_runtime.h>
#include <stdint.h>

#define N_ROWS 8192
#define C_IN   4096
#define C_OUT  4096
#define NCHUNK (C_IN / 64)         // 64 chunks of BK=64
#define MT_STRIDE (128 * 1024)     // bytes per 32-row slab in frag file

typedef int v4i  __attribute__((ext_vector_type(4)));
typedef int v16i __attribute__((ext_vector_type(16)));

// ======================================================================
// pack (LDS-transpose): coalesced reads -> frag-ordered linear writes
// Each block: one slab = 32 rows x 512 cols (mt, cg) -> 16KB frag bytes.
//   frag[mt][kb][(hi*32+r)*16 + j] = sign(src[mt*32+r][kb*32+hi*16+j])
// Thread t: r = t>>3 (row), lc = t&7; iter it covers cols lc*4 + 32*it.
// LDS write offs: it*1024 + (hi*32+r)*16 + (lc&3)*4  -> 2-way bank (free).
// ======================================================================
__global__ void pack_all_kernel(const float* __restrict__ x,
                                const float* __restrict__ w,
                                uint8_t* __restrict__ xf,
                                uint8_t* __restrict__ wf,
                                float* __restrict__ partials) {
    __shared__ uint32_t tile[4096];   // 16 KB
    __shared__ float sacc[4];

    const int b = blockIdx.x;
    const float* src; uint8_t* dst; int slab;
    if (b < 2048) { src = x; dst = xf; slab = b; }        // x: 256 mt x 8 cg
    else          { src = w; dst = wf; slab = b - 2048; } // w: 128 mt x 8 cg
    const int mt = slab >> 3, cg = slab & 7;

    const int t  = threadIdx.x;
    const int r  = t >> 3, lc = t & 7;
    const int hi = lc >> 2, jq = lc & 3;

    const float4* base = (const float4*)(src + (size_t)(mt * 32 + r) * C_IN + cg * 512) + lc;
    float acc = 0.f;
#pragma unroll
    for (int it = 0; it < 16; ++it) {
        float4 v = base[it * 8];
        uint32_t bb = (v.x > 0.f ? 0x01u : 0xFFu)
                    | (v.y > 0.f ? 0x01u : 0xFFu) << 8
                    | (v.z > 0.f ? 0x01u : 0xFFu) << 16
                    | (v.w > 0.f ? 0x01u : 0xFFu) << 24;
        acc += fabsf(v.x) + fabsf(v.y) + fabsf(v.z) + fabsf(v.w);
        tile[it * 256 + (hi * 32 + r) * 4 + jq] = bb;
    }
    __syncthreads();
    // copy 16KB tile (1024 uint4) with 256 threads -> p = 0..3  (round-4 bug: was 0..7)
    uint4* gout = (uint4*)(dst + (size_t)mt * MT_STRIDE + (size_t)cg * 16384);
    const uint4* lin = (const uint4*)tile;
#pragma unroll
    for (int p = 0; p < 4; ++p) gout[p * 256 + t] = lin[p * 256 + t];

    for (int off = 32; off > 0; off >>= 1) acc += __shfl_down(acc, off, 64);
    const int lane = t & 63, wv = t >> 6;
    if (lane == 0) sacc[wv] = acc;
    __syncthreads();
    if (t == 0) {
        float s = 0.f;
        for (int i = 0; i < 4; ++i) s += sacc[i];
        partials[b] = s;
    }
}

// ---- deterministic final reduction -> alpha*betta ----
__global__ void finalize_kernel(const float* __restrict__ part_x, int nx,
                                const float* __restrict__ part_w, int nw,
                                float* __restrict__ out_ab) {
    __shared__ float s[256];
    float ax = 0.f;
    for (int i = threadIdx.x; i < nx; i += 256) ax += part_x[i];
    s[threadIdx.x] = ax; __syncthreads();
    for (int st = 128; st > 0; st >>= 1) {
        if (threadIdx.x < st) s[threadIdx.x] += s[threadIdx.x + st];
        __syncthreads();
    }
    float sumx = s[0];
    __syncthreads();
    float aw = 0.f;
    for (int i = threadIdx.x; i < nw; i += 256) aw += part_w[i];
    s[threadIdx.x] = aw; __syncthreads();
    for (int st = 128; st > 0; st >>= 1) {
        if (threadIdx.x < st) s[threadIdx.x] += s[threadIdx.x + st];
        __syncthreads();
    }
    if (threadIdx.x == 0) {
        float sumw = s[0];
        float alpha = sumw / (float)((long long)C_OUT * C_IN);
        float betta = sumx / (float)((long long)N_ROWS * C_IN);
        out_ab[0] = alpha * betta;
    }
}

// ======================================================================
// i8 MFMA GEMM, 8-phase-per-2-halves schedule with counted vmcnt.
// 256x256 tile, 8 waves (2x4), BK=64 split into kk-halves of 32.
// LDS [dbuf][kk][mat][8KB] = 64KB. One global_load_lds issued per phase;
// s_waitcnt vmcnt(2) only at P1/P3 exits (2 loads always in flight).
// ======================================================================
#define MFMA_I8(a, b, c) __builtin_amdgcn_mfma_i32_32x32x32_i8((a), (b), (c), 0, 0, 0)

__launch_bounds__(512)
__global__ void xnor_gemm_i8(const uint8_t* __restrict__ Afrag,
                             const uint8_t* __restrict__ Bfrag,
                             const float* __restrict__ bias,
                             const float* __restrict__ ab_ptr,
                             float* __restrict__ out) {
    __shared__ __align__(16) uint8_t lds[2][2][2][8192];  // 64 KB

    const int t    = threadIdx.x;
    const int lane = t & 63;
    const int hi   = lane >> 5;
    const int r    = lane & 31;
    const int wid  = t >> 6;
    const int wr   = wid >> 2;   // 0..1
    const int wc   = wid & 3;    // 0..3

    // XCD-aware swizzle over 512 blocks (divisible by 8)
    const int id  = blockIdx.x;
    const int swz = (id & 7) * 64 + (id >> 3);
    const int brow = (swz >> 4) * 256;
    const int bcol = (swz & 15) * 256;

    const uint8_t* Abase = Afrag + (size_t)(brow >> 5) * MT_STRIDE;
    const uint8_t* Bbase = Bfrag + (size_t)(bcol >> 5) * MT_STRIDE;
    // per-thread staging source offset: mtl = t>>6, ln = t&63
    const size_t soff = (size_t)(t >> 6) * MT_STRIDE + (size_t)(t & 63) * 16;

#define STAGE_A(buf, kk, c)                                                            \
    __builtin_amdgcn_global_load_lds(                                                  \
        (const __attribute__((address_space(1))) void*)(Abase + soff + (size_t)((c) * 2 + (kk)) * 1024), \
        (__attribute__((address_space(3))) void*)(&lds[buf][kk][0][t * 16]), 16, 0, 0)
#define STAGE_B(buf, kk, c)                                                            \
    __builtin_amdgcn_global_load_lds(                                                  \
        (const __attribute__((address_space(1))) void*)(Bbase + soff + (size_t)((c) * 2 + (kk)) * 1024), \
        (__attribute__((address_space(3))) void*)(&lds[buf][kk][1][t * 16]), 16, 0, 0)

#define LDA(buf, kk, m) (*(const v4i*)(&lds[buf][kk][0][(((wr * 4 + (m)) * 64) + lane) * 16]))
#define LDB(buf, kk, n) (*(const v4i*)(&lds[buf][kk][1][(((wc * 2 + (n)) * 64) + lane) * 16]))

    v16i acc[4][2] = {};

    // prologue: stage chunk 0, both halves (FIFO: A00,B00,A01,B01)
    STAGE_A(0, 0, 0); STAGE_B(0, 0, 0); STAGE_A(0, 1, 0); STAGE_B(0, 1, 0);
    asm volatile("s_waitcnt vmcnt(2)" ::: "memory");   // H(0,0) landed
    __builtin_amdgcn_s_barrier();

#pragma unroll 2
    for (int ck = 0; ck < NCHUNK; ++ck) {
        const int buf  = ck & 1, nb = buf ^ 1;
        const int c1   = ck + 1;
        const bool more = (c1 < NCHUNK);

        // ---- P0 (kk=0, m=0..1) ----
        v4i a0 = LDA(buf, 0, 0), a1 = LDA(buf, 0, 1);
        v4i b0 = LDB(buf, 0, 0), b1 = LDB(buf, 0, 1);
        if (more) STAGE_A(nb, 0, c1);
        __builtin_amdgcn_s_barrier();
        __builtin_amdgcn_s_setprio(1);
        acc[0][0] = MFMA_I8(a0, b0, acc[0][0]);
        acc[0][1] = MFMA_I8(a0, b1, acc[0][1]);
        acc[1][0] = MFMA_I8(a1, b0, acc[1][0]);
        acc[1][1] = MFMA_I8(a1, b1, acc[1][1]);
        __builtin_amdgcn_s_setprio(0);
        __builtin_amdgcn_s_barrier();

        // ---- P1 (kk=0, m=2..3) ----
        v4i a2 = LDA(buf, 0, 2), a3 = LDA(buf, 0, 3);
        if (more) STAGE_B(nb, 0, c1);
        __builtin_amdgcn_s_barrier();
        __builtin_amdgcn_s_setprio(1);
        acc[2][0] = MFMA_I8(a2, b0, acc[2][0]);
        acc[2][1] = MFMA_I8(a2, b1, acc[2][1]);
        acc[3][0] = MFMA_I8(a3, b0, acc[3][0]);
        acc[3][1] = MFMA_I8(a3, b1, acc[3][1]);
        __builtin_amdgcn_s_setprio(0);
        if (more) { asm volatile("s_waitcnt vmcnt(2)" ::: "memory"); }  // H(ck,1) landed
        else      { asm volatile("s_waitcnt vmcnt(0)" ::: "memory"); }
        __builtin_amdgcn_s_barrier();

        // ---- P2 (kk=1, m=0..1) ----
        a0 = LDA(buf, 1, 0); a1 = LDA(buf, 1, 1);
        b0 = LDB(buf, 1, 0); b1 = LDB(buf, 1, 1);
        if (more) STAGE_A(nb, 1, c1);
        __builtin_amdgcn_s_barrier();
        __builtin_amdgcn_s_setprio(1);
        acc[0][0] = MFMA_I8(a0, b0, acc[0][0]);
        acc[0][1] = MFMA_I8(a0, b1, acc[0][1]);
        acc[1][0] = MFMA_I8(a1, b0, acc[1][0]);
        acc[1][1] = MFMA_I8(a1, b1, acc[1][1]);
        __builtin_amdgcn_s_setprio(0);
        __builtin_amdgcn_s_barrier();

        // ---- P3 (kk=1, m=2..3) ----
        a2 = LDA(buf, 1, 2); a3 = LDA(buf, 1, 3);
        if (more) STAGE_B(nb, 1, c1);
        __builtin_amdgcn_s_barrier();
        __builtin_amdgcn_s_setprio(1);
        acc[2][0] = MFMA_I8(a2, b0, acc[2][0]);
        acc[2][1] = MFMA_I8(a2, b1, acc[2][1]);
        acc[3][0] = MFMA_I8(a3, b0, acc[3][0]);
        acc[3][1] = MFMA_I8(a3, b1, acc[3][1]);
        __builtin_amdgcn_s_setprio(0);
        if (more) { asm volatile("s_waitcnt vmcnt(2)" ::: "memory"); }  // H(c1,0) landed
        else      { asm volatile("s_waitcnt vmcnt(0)" ::: "memory"); }
        __builtin_amdgcn_s_barrier();
    }

    const float ab = ab_ptr[0];
#pragma unroll
    for (int m = 0; m < 4; ++m) {
#pragma unroll
        for (int n = 0; n < 2; ++n) {
            int col = bcol + wc * 64 + n * 32 + r;
            float bv = bias[col];
#pragma unroll
            for (int reg = 0; reg < 16; ++reg) {
                int rowf = (reg & 3) + 8 * (reg >> 2) + 4 * hi;   // C/D layout (m74/m101)
                int grow = brow + wr * 128 + m * 32 + rowf;
                out[(size_t)grow * C_OUT + col] = (float)acc[m][n][reg] * ab + bv;
            }
        }
    }
#undef STAGE_A
#undef STAGE_B
#undef LDA
#undef LDB
}

// ======================================================================
extern "C" void kernel_launch(void* const* d_in, const int* in_sizes, int n_in,
                              void* d_out, int out_size, void* d_ws, size_t ws_size,
                              hipStream_t stream) {
    const float* x    = (const float*)d_in[0];
    const float* w    = (const float*)d_in[1];
    const float* bias = (const float*)d_in[2];
    float* out = (float*)d_out;

    char* ws = (char*)d_ws;
    float* red      = (float*)ws;      // red[0] = alpha*betta
    float* partials = red + 16;        // 3072 partials (x: 0..2047, w: 2048..3071)
    uint8_t* xs  = (uint8_t*)(ws + 16384);       // 33.55 MB frag file
    uint8_t* wsg = xs + (size_t)N_ROWS * C_IN;   // 16.78 MB frag file

    pack_all_kernel<<<3072, 256, 0, stream>>>(x, w, xs, wsg, partials);
    finalize_kernel<<<1, 256, 0, stream>>>(partials, 2048, partials + 2048, 1024, red);

    dim3 grid((N_ROWS / 256) * (C_OUT / 256));  // 512
    xnor_gemm_i8<<<grid, 512, 0, stream>>>(xs, wsg, bias, red, out);
}

// Round 6
// 131.193 us; speedup vs baseline: 3.1587x; 1.4367x over previous
//
#include <hip/hip_runtime.h>
#include <stdint.h>

#define N_ROWS 8192
#define C_IN   4096
#define C_OUT  4096
#define NCHUNK (C_IN / 64)     // 64 chunks of BK=64 (one 32x32x64 MFMA K-slab)
#define MT4    65536           // bytes per 32-row slab in fp4 frag file (64 kb x 1024B)

typedef int   v4i  __attribute__((ext_vector_type(4)));
typedef int   v8i  __attribute__((ext_vector_type(8)));
typedef float v16f __attribute__((ext_vector_type(16)));

// ======================================================================
// pack (LDS-transpose): f32 -> fp4 e2m1 sign (+1 -> 0x2, -1 -> 0xA),
// frag-ordered: frag[mt][kb][lane(=hi*32+r)*16 + byte j] holds nibbles for
// k = hi*32 + 2j (lo) and hi*32 + 2j+1 (hi). Same bijection for A and B,
// so any consistent HW k-order gives the exact dot product.
// Block = one slab: 32 rows x 512 cols -> 8 KB frag bytes.
// Index algebra collapses to tile16[it*256 + t] (linear; 2-way banks = free).
// ======================================================================
__global__ void pack_all_kernel(const float* __restrict__ x,
                                const float* __restrict__ w,
                                uint8_t* __restrict__ xf,
                                uint8_t* __restrict__ wf,
                                float* __restrict__ partials) {
    __shared__ __align__(16) uint16_t tile16[4096];   // 8 KB
    __shared__ float sacc[4];

    const int b = blockIdx.x;
    const float* src; uint8_t* dst; int slab;
    if (b < 2048) { src = x; dst = xf; slab = b; }        // x: 256 mt x 8 cg
    else          { src = w; dst = wf; slab = b - 2048; } // w: 128 mt x 8 cg
    const int mt = slab >> 3, cg = slab & 7;

    const int t = threadIdx.x;
    const int r = t >> 3, lc = t & 7;

    const float4* base = (const float4*)(src + (size_t)(mt * 32 + r) * C_IN + cg * 512) + lc;
    float acc = 0.f;
#pragma unroll
    for (int it = 0; it < 16; ++it) {
        float4 v = base[it * 8];
        uint16_t nv = (uint16_t)((v.x > 0.f ? 0x2u : 0xAu)
                               | (v.y > 0.f ? 0x2u : 0xAu) << 4
                               | (v.z > 0.f ? 0x2u : 0xAu) << 8
                               | (v.w > 0.f ? 0x2u : 0xAu) << 12);
        acc += fabsf(v.x) + fabsf(v.y) + fabsf(v.z) + fabsf(v.w);
        tile16[it * 256 + t] = nv;
    }
    __syncthreads();
    // copy 8 KB (512 uint4) with 256 threads
    uint4* gout = (uint4*)(dst + (size_t)mt * MT4 + (size_t)cg * 8192);
    const uint4* lin = (const uint4*)tile16;
#pragma unroll
    for (int p = 0; p < 2; ++p) gout[p * 256 + t] = lin[p * 256 + t];

    for (int off = 32; off > 0; off >>= 1) acc += __shfl_down(acc, off, 64);
    const int lane = t & 63, wv = t >> 6;
    if (lane == 0) sacc[wv] = acc;
    __syncthreads();
    if (t == 0) {
        float s = 0.f;
        for (int i = 0; i < 4; ++i) s += sacc[i];
        partials[b] = s;
    }
}

// ---- deterministic final reduction -> alpha*betta ----
__global__ void finalize_kernel(const float* __restrict__ part_x, int nx,
                                const float* __restrict__ part_w, int nw,
                                float* __restrict__ out_ab) {
    __shared__ float s[256];
    float ax = 0.f;
    for (int i = threadIdx.x; i < nx; i += 256) ax += part_x[i];
    s[threadIdx.x] = ax; __syncthreads();
    for (int st = 128; st > 0; st >>= 1) {
        if (threadIdx.x < st) s[threadIdx.x] += s[threadIdx.x + st];
        __syncthreads();
    }
    float sumx = s[0];
    __syncthreads();
    float aw = 0.f;
    for (int i = threadIdx.x; i < nw; i += 256) aw += part_w[i];
    s[threadIdx.x] = aw; __syncthreads();
    for (int st = 128; st > 0; st >>= 1) {
        if (threadIdx.x < st) s[threadIdx.x] += s[threadIdx.x + st];
        __syncthreads();
    }
    if (threadIdx.x == 0) {
        float sumw = s[0];
        float alpha = sumw / (float)((long long)C_OUT * C_IN);
        float betta = sumx / (float)((long long)N_ROWS * C_IN);
        out_ab[0] = alpha * betta;
    }
}

// ======================================================================
// MX-FP4 MFMA GEMM: 256x256 tile, 8 waves (2x4), BK=64 = one K-slab/MFMA.
// 4-deep LDS buffers (32 KB); stage chunk c+2 during c; vmcnt(2) entry
// (counted, loads issued ~2 chunks = ~2500 cyc ahead of use);
// ONE barrier per chunk. All LDS reads base+lane*16: conflict-free.
// Scale = e8m0 127 (=1.0); fp4 data in low 4 regs of the v8i operand.
// ======================================================================
#define MFMA_FP4(a, b, c) \
    __builtin_amdgcn_mfma_scale_f32_32x32x64_f8f6f4((a), (b), (c), 4, 4, 0, 127, 0, 127)

__launch_bounds__(512)
__global__ void xnor_gemm_fp4(const uint8_t* __restrict__ Afrag,
                              const uint8_t* __restrict__ Bfrag,
                              const float* __restrict__ bias,
                              const float* __restrict__ ab_ptr,
                              float* __restrict__ out) {
    __shared__ __align__(16) uint8_t lds[4][2][8192];  // 64 KB

    const int t    = threadIdx.x;
    const int lane = t & 63;
    const int hi   = lane >> 5;
    const int r    = lane & 31;
    const int wid  = t >> 6;
    const int wr   = wid >> 2;   // 0..1
    const int wc   = wid & 3;    // 0..3

    // XCD-aware swizzle over 512 blocks (divisible by 8)
    const int id  = blockIdx.x;
    const int swz = (id & 7) * 64 + (id >> 3);
    const int brow = (swz >> 4) * 256;
    const int bcol = (swz & 15) * 256;

    const uint8_t* Abase = Afrag + (size_t)(brow >> 5) * MT4;
    const uint8_t* Bbase = Bfrag + (size_t)(bcol >> 5) * MT4;
    // per-thread staging src: slab mtl = t>>6, frag-lane ln = t&63
    const size_t soff = (size_t)(t >> 6) * MT4 + (size_t)(t & 63) * 16;

#define STG(buf, c)                                                                     \
    do {                                                                                \
        __builtin_amdgcn_global_load_lds(                                               \
            (const __attribute__((address_space(1))) void*)(Abase + soff + (size_t)(c) * 1024), \
            (__attribute__((address_space(3))) void*)(&lds[buf][0][t * 16]), 16, 0, 0); \
        __builtin_amdgcn_global_load_lds(                                               \
            (const __attribute__((address_space(1))) void*)(Bbase + soff + (size_t)(c) * 1024), \
            (__attribute__((address_space(3))) void*)(&lds[buf][1][t * 16]), 16, 0, 0); \
    } while (0)

    v16f acc[4][2] = {};

    STG(0, 0); STG(1, 1);   // 4 loads in flight (A0,B0,A1,B1)

#pragma unroll 4
    for (int ck = 0; ck < NCHUNK; ++ck) {
        const int buf = ck & 3;
        if (ck < NCHUNK - 2) { asm volatile("s_waitcnt vmcnt(2)" ::: "memory"); }
        else                 { asm volatile("s_waitcnt vmcnt(0)" ::: "memory"); }
        __builtin_amdgcn_s_barrier();

        v4i a4[4], b4[2];
#pragma unroll
        for (int m = 0; m < 4; ++m)
            a4[m] = *(const v4i*)(&lds[buf][0][((wr * 4 + m) * 64 + lane) * 16]);
#pragma unroll
        for (int n = 0; n < 2; ++n)
            b4[n] = *(const v4i*)(&lds[buf][1][((wc * 2 + n) * 64 + lane) * 16]);

        if (ck + 2 < NCHUNK) STG((ck + 2) & 3, ck + 2);

        v8i a8[4], b8[2];
#pragma unroll
        for (int m = 0; m < 4; ++m) {
            v8i v = {a4[m][0], a4[m][1], a4[m][2], a4[m][3], 0, 0, 0, 0};
            a8[m] = v;
        }
#pragma unroll
        for (int n = 0; n < 2; ++n) {
            v8i v = {b4[n][0], b4[n][1], b4[n][2], b4[n][3], 0, 0, 0, 0};
            b8[n] = v;
        }

        __builtin_amdgcn_s_setprio(1);
#pragma unroll
        for (int m = 0; m < 4; ++m)
#pragma unroll
            for (int n = 0; n < 2; ++n)
                acc[m][n] = MFMA_FP4(a8[m], b8[n], acc[m][n]);
        __builtin_amdgcn_s_setprio(0);
    }

    const float ab = ab_ptr[0];
#pragma unroll
    for (int m = 0; m < 4; ++m) {
#pragma unroll
        for (int n = 0; n < 2; ++n) {
            int col = bcol + wc * 64 + n * 32 + r;
            float bv = bias[col];
#pragma unroll
            for (int reg = 0; reg < 16; ++reg) {
                int rowf = (reg & 3) + 8 * (reg >> 2) + 4 * hi;   // C/D layout (shape-determined)
                int grow = brow + wr * 128 + m * 32 + rowf;
                out[(size_t)grow * C_OUT + col] = acc[m][n][reg] * ab + bv;
            }
        }
    }
#undef STG
}

// ======================================================================
extern "C" void kernel_launch(void* const* d_in, const int* in_sizes, int n_in,
                              void* d_out, int out_size, void* d_ws, size_t ws_size,
                              hipStream_t stream) {
    const float* x    = (const float*)d_in[0];
    const float* w    = (const float*)d_in[1];
    const float* bias = (const float*)d_in[2];
    float* out = (float*)d_out;

    char* ws = (char*)d_ws;
    float* red      = (float*)ws;      // red[0] = alpha*betta
    float* partials = red + 16;        // 3072 partials (x: 0..2047, w: 2048..3071)
    uint8_t* xs  = (uint8_t*)(ws + 16384);             // 16 MB fp4 frag file (x)
    uint8_t* wsg = xs + (size_t)N_ROWS * C_IN / 2;     // 8 MB fp4 frag file (w)

    pack_all_kernel<<<3072, 256, 0, stream>>>(x, w, xs, wsg, partials);
    finalize_kernel<<<1, 256, 0, stream>>>(partials, 2048, partials + 2048, 1024, red);

    dim3 grid((N_ROWS / 256) * (C_OUT / 256));  // 512
    xnor_gemm_fp4<<<grid, 512, 0, stream>>>(xs, wsg, bias, red, out);
}

// Round 7
// 127.961 us; speedup vs baseline: 3.2385x; 1.0253x over previous
//
#include <hip/hip_runtime.h>
#include <stdint.h>

#define N_ROWS 8192
#define C_IN   4096
#define C_OUT  4096
#define NCHUNK (C_IN / 128)    // 32 chunks of BK=128 (two 32x32x64 K-slabs)
#define MT4    65536           // bytes per 32-row slab in fp4 frag file

typedef int   v4i  __attribute__((ext_vector_type(4)));
typedef int   v8i  __attribute__((ext_vector_type(8)));
typedef float v16f __attribute__((ext_vector_type(16)));

// ======================================================================
// pack (LDS-transpose): f32 -> fp4 e2m1 sign (+1 -> 0x2, -1 -> 0xA),
// frag-ordered: frag[mt][kb][lane*16 + j] = nibbles for 2 k's. Same
// bijection for A and B -> exact dot regardless of HW k-order.
// (verified on HW in round 6)
// ======================================================================
__global__ void pack_all_kernel(const float* __restrict__ x,
                                const float* __restrict__ w,
                                uint8_t* __restrict__ xf,
                                uint8_t* __restrict__ wf,
                                float* __restrict__ partials) {
    __shared__ __align__(16) uint16_t tile16[4096];   // 8 KB
    __shared__ float sacc[4];

    const int b = blockIdx.x;
    const float* src; uint8_t* dst; int slab;
    if (b < 2048) { src = x; dst = xf; slab = b; }        // x: 256 mt x 8 cg
    else          { src = w; dst = wf; slab = b - 2048; } // w: 128 mt x 8 cg
    const int mt = slab >> 3, cg = slab & 7;

    const int t = threadIdx.x;
    const int r = t >> 3, lc = t & 7;

    const float4* base = (const float4*)(src + (size_t)(mt * 32 + r) * C_IN + cg * 512) + lc;
    float acc = 0.f;
#pragma unroll
    for (int it = 0; it < 16; ++it) {
        float4 v = base[it * 8];
        uint16_t nv = (uint16_t)((v.x > 0.f ? 0x2u : 0xAu)
                               | (v.y > 0.f ? 0x2u : 0xAu) << 4
                               | (v.z > 0.f ? 0x2u : 0xAu) << 8
                               | (v.w > 0.f ? 0x2u : 0xAu) << 12);
        acc += fabsf(v.x) + fabsf(v.y) + fabsf(v.z) + fabsf(v.w);
        tile16[it * 256 + t] = nv;
    }
    __syncthreads();
    uint4* gout = (uint4*)(dst + (size_t)mt * MT4 + (size_t)cg * 8192);
    const uint4* lin = (const uint4*)tile16;
#pragma unroll
    for (int p = 0; p < 2; ++p) gout[p * 256 + t] = lin[p * 256 + t];

    for (int off = 32; off > 0; off >>= 1) acc += __shfl_down(acc, off, 64);
    const int lane = t & 63, wv = t >> 6;
    if (lane == 0) sacc[wv] = acc;
    __syncthreads();
    if (t == 0) {
        float s = 0.f;
        for (int i = 0; i < 4; ++i) s += sacc[i];
        partials[b] = s;
    }
}

// ---- deterministic final reduction -> alpha*betta ----
__global__ void finalize_kernel(const float* __restrict__ part_x, int nx,
                                const float* __restrict__ part_w, int nw,
                                float* __restrict__ out_ab) {
    __shared__ float s[256];
    float ax = 0.f;
    for (int i = threadIdx.x; i < nx; i += 256) ax += part_x[i];
    s[threadIdx.x] = ax; __syncthreads();
    for (int st = 128; st > 0; st >>= 1) {
        if (threadIdx.x < st) s[threadIdx.x] += s[threadIdx.x + st];
        __syncthreads();
    }
    float sumx = s[0];
    __syncthreads();
    float aw = 0.f;
    for (int i = threadIdx.x; i < nw; i += 256) aw += part_w[i];
    s[threadIdx.x] = aw; __syncthreads();
    for (int st = 128; st > 0; st >>= 1) {
        if (threadIdx.x < st) s[threadIdx.x] += s[threadIdx.x + st];
        __syncthreads();
    }
    if (threadIdx.x == 0) {
        float sumw = s[0];
        float alpha = sumw / (float)((long long)C_OUT * C_IN);
        float betta = sumx / (float)((long long)N_ROWS * C_IN);
        out_ab[0] = alpha * betta;
    }
}

// ======================================================================
// MX-FP4 MFMA GEMM: 128x256 tile, 8 waves (2x4), per-wave 64x64 (64 acc).
// BK=128 chunks, 3-deep LDS buffers (24KB each, 72KB total) -> 2 blocks/CU
// at 4 waves/SIMD (launch_bounds cap 128 regs). Uniform 3 loads/thread/chunk;
// counted vmcnt(3), drained only at the last chunk. One barrier per chunk.
// fp4 operand: HW reads only low 4 dwords -> undef high half (no movs).
// ======================================================================
#define MFMA_FP4(a, b, c) \
    __builtin_amdgcn_mfma_scale_f32_32x32x64_f8f6f4((a), (b), (c), 4, 4, 0, 127, 0, 127)
#define UP8(v4) __builtin_shufflevector((v4), (v4), 0, 1, 2, 3, -1, -1, -1, -1)

__launch_bounds__(512, 4)
__global__ void xnor_gemm_fp4(const uint8_t* __restrict__ Afrag,
                              const uint8_t* __restrict__ Bfrag,
                              const float* __restrict__ bias,
                              const float* __restrict__ ab_ptr,
                              float* __restrict__ out) {
    // per buffer: A 8KB (4 slabs x 2 kb) then B 16KB (8 slabs x 2 kb)
    __shared__ __align__(16) uint8_t lds[3][24576];  // 72 KB

    const int t    = threadIdx.x;
    const int lane = t & 63;
    const int hi   = lane >> 5;
    const int r    = lane & 31;
    const int wid  = t >> 6;
    const int wr   = wid >> 2;   // 0..1
    const int wc   = wid & 3;    // 0..3

    // XCD-aware swizzle over 1024 blocks (divisible by 8)
    const int id  = blockIdx.x;
    const int swz = (id & 7) * 128 + (id >> 3);
    const int brow = (swz >> 4) * 128;   // 64 m-tiles
    const int bcol = (swz & 15) * 256;   // 16 n-tiles

    const uint8_t* Abase = Afrag + (size_t)(brow >> 5) * MT4;
    const uint8_t* Bbase = Bfrag + (size_t)(bcol >> 5) * MT4;

    // staging source offsets (per-chunk advance = 2048 B = 2 kb slabs)
    const int pA = t;                   // 512 A pieces
    const int pB0 = t, pB1 = t + 512;   // 1024 B pieces
    const size_t offA  = (size_t)(pA  >> 7) * MT4 + (size_t)((pA  >> 6) & 1) * 1024 + (size_t)(pA  & 63) * 16;
    const size_t offB0 = (size_t)(pB0 >> 7) * MT4 + (size_t)((pB0 >> 6) & 1) * 1024 + (size_t)(pB0 & 63) * 16;
    const size_t offB1 = (size_t)(pB1 >> 7) * MT4 + (size_t)((pB1 >> 6) & 1) * 1024 + (size_t)(pB1 & 63) * 16;

#define STG(buf, c)                                                                     \
    do {                                                                                \
        size_t ka = (size_t)(c) * 2048;                                                 \
        __builtin_amdgcn_global_load_lds(                                               \
            (const __attribute__((address_space(1))) void*)(Abase + offA + ka),         \
            (__attribute__((address_space(3))) void*)(&lds[buf][t * 16]), 16, 0, 0);    \
        __builtin_amdgcn_global_load_lds(                                               \
            (const __attribute__((address_space(1))) void*)(Bbase + offB0 + ka),        \
            (__attribute__((address_space(3))) void*)(&lds[buf][8192 + pB0 * 16]), 16, 0, 0); \
        __builtin_amdgcn_global_load_lds(                                               \
            (const __attribute__((address_space(1))) void*)(Bbase + offB1 + ka),        \
            (__attribute__((address_space(3))) void*)(&lds[buf][8192 + pB1 * 16]), 16, 0, 0); \
    } while (0)

    // LDS fragment reads (conflict-free: uniform base + lane*16)
#define LDA(buf, m, ks) (*(const v4i*)(&lds[buf][((wr * 2 + (m)) * 2048) + (ks) * 1024 + lane * 16]))
#define LDB(buf, n, ks) (*(const v4i*)(&lds[buf][8192 + ((wc * 2 + (n)) * 2048) + (ks) * 1024 + lane * 16]))

    v16f acc[2][2] = {};

    STG(0, 0); STG(1, 1);   // 6 loads in flight

    for (int ck = 0; ck < NCHUNK; ++ck) {
        const int buf = ck % 3;
        if (ck < NCHUNK - 1) { asm volatile("s_waitcnt vmcnt(3)" ::: "memory"); }
        else                 { asm volatile("s_waitcnt vmcnt(0)" ::: "memory"); }
        __builtin_amdgcn_s_barrier();

        // ---- ks = 0 ----
        v4i a0 = LDA(buf, 0, 0), a1 = LDA(buf, 1, 0);
        v4i b0 = LDB(buf, 0, 0), b1 = LDB(buf, 1, 0);
        if (ck + 2 < NCHUNK) STG((ck + 2) % 3, ck + 2);
        __builtin_amdgcn_s_setprio(1);
        acc[0][0] = MFMA_FP4(UP8(a0), UP8(b0), acc[0][0]);
        acc[0][1] = MFMA_FP4(UP8(a0), UP8(b1), acc[0][1]);
        acc[1][0] = MFMA_FP4(UP8(a1), UP8(b0), acc[1][0]);
        acc[1][1] = MFMA_FP4(UP8(a1), UP8(b1), acc[1][1]);
        __builtin_amdgcn_s_setprio(0);

        // ---- ks = 1 ----
        a0 = LDA(buf, 0, 1); a1 = LDA(buf, 1, 1);
        b0 = LDB(buf, 0, 1); b1 = LDB(buf, 1, 1);
        __builtin_amdgcn_s_setprio(1);
        acc[0][0] = MFMA_FP4(UP8(a0), UP8(b0), acc[0][0]);
        acc[0][1] = MFMA_FP4(UP8(a0), UP8(b1), acc[0][1]);
        acc[1][0] = MFMA_FP4(UP8(a1), UP8(b0), acc[1][0]);
        acc[1][1] = MFMA_FP4(UP8(a1), UP8(b1), acc[1][1]);
        __builtin_amdgcn_s_setprio(0);
    }

    const float ab = ab_ptr[0];
#pragma unroll
    for (int m = 0; m < 2; ++m) {
#pragma unroll
        for (int n = 0; n < 2; ++n) {
            int col = bcol + (wc * 2 + n) * 32 + r;
            float bv = bias[col];
#pragma unroll
            for (int reg = 0; reg < 16; ++reg) {
                int rowf = (reg & 3) + 8 * (reg >> 2) + 4 * hi;   // C/D layout (shape-determined)
                int grow = brow + (wr * 2 + m) * 32 + rowf;
                out[(size_t)grow * C_OUT + col] = acc[m][n][reg] * ab + bv;
            }
        }
    }
#undef STG
#undef LDA
#undef LDB
}

// ======================================================================
extern "C" void kernel_launch(void* const* d_in, const int* in_sizes, int n_in,
                              void* d_out, int out_size, void* d_ws, size_t ws_size,
                              hipStream_t stream) {
    const float* x    = (const float*)d_in[0];
    const float* w    = (const float*)d_in[1];
    const float* bias = (const float*)d_in[2];
    float* out = (float*)d_out;

    char* ws = (char*)d_ws;
    float* red      = (float*)ws;      // red[0] = alpha*betta
    float* partials = red + 16;        // 3072 partials (x: 0..2047, w: 2048..3071)
    uint8_t* xs  = (uint8_t*)(ws + 16384);             // 16 MB fp4 frag file (x)
    uint8_t* wsg = xs + (size_t)N_ROWS * C_IN / 2;     // 8 MB fp4 frag file (w)

    pack_all_kernel<<<3072, 256, 0, stream>>>(x, w, xs, wsg, partials);
    finalize_kernel<<<1, 256, 0, stream>>>(partials, 2048, partials + 2048, 1024, red);

    dim3 grid((N_ROWS / 128) * (C_OUT / 256));  // 1024
    xnor_gemm_fp4<<<grid, 512, 0, stream>>>(xs, wsg, bias, red, out);
}